// Round 12
// baseline (54.016 us; speedup 1.0000x reference)
//
#include <hip/hip_runtime.h>
#include <hip/hip_fp16.h>

typedef _Float16 f16x2 __attribute__((ext_vector_type(2)));
typedef _Float16 f16x8 __attribute__((ext_vector_type(8)));
typedef float    f32x4 __attribute__((ext_vector_type(4)));

#define M_DIM   32
#define K_DIM   8192
#define N_DIM   28672
#define KWORDS  1024           // K/8 packed words per weight row
#define NKB     128            // K/64 scale blocks per row
#define NBLKN   56             // N/512 n-blocks
#define NSPLIT  8
#define OUT_ELEMS (M_DIM * N_DIM)
#define X16_BYTES (KWORDS * M_DIM * 16)   // 512 KB fragment-layout x

__device__ __forceinline__ unsigned pkrtz(float a, float b) {
    return __builtin_bit_cast(unsigned, __builtin_amdgcn_cvt_pkrtz(a, b));
}

// x -> fragment-layout fp16: x16[w][m] = 8 fp16 of row m, pairs (k=8w+p, 8w+p+4)
// (identical k-permutation to the nibble unpack, so MFMA k-sums match)
__global__ __launch_bounds__(256) void x_transform(const float* __restrict__ x,
                                                   uint4* __restrict__ x16) {
    const int idx = blockIdx.x * 256 + threadIdx.x;   // w*32 + m
    const int w = idx >> 5, m = idx & 31;
    const float4* p = (const float4*)(x + (size_t)m * K_DIM + w * 8);
    float4 f0 = p[0], f1 = p[1];
    uint4 v = { pkrtz(f0.x, f1.x), pkrtz(f0.y, f1.y),
                pkrtz(f0.z, f1.z), pkrtz(f0.w, f1.w) };
    x16[idx] = v;
}

__global__ __launch_bounds__(256) void wql_init(const float* __restrict__ bias,
                                                float* __restrict__ out) {
    int n = blockIdx.x * 256 + threadIdx.x;
    int m = blockIdx.y;
    out[(size_t)m * N_DIM + n] = bias[n];
}

// 8 nibbles -> 8 dequantized fp16. Pair p = nibbles (p,p+4); 0x6400|q = 1024+q
// exact; cpk = -(1024+8+zq) exact; (f+cpk) exact small int; one rounding on *spk.
__device__ __forceinline__ f16x8 dq_word(unsigned W, f16x2 spk, f16x2 cpk) {
    union { f16x2 h[4]; f16x8 v; } r;
#pragma unroll
    for (int p = 0; p < 4; ++p) {
        unsigned raw = ((W >> (4 * p)) & 0x000F000Fu) | 0x64006400u;
        f16x2 f = __builtin_bit_cast(f16x2, raw);
        r.h[p] = (f + cpk) * spk;
    }
    return r.v;
}

// SMALL-CODE design (R12): same dataflow as R11 (one barrier, 64 KB x16 slab,
// barrier-free n/section loops) but ROLLED: #pragma unroll 1 on the it- and
// s-loops keeps the hot body ~170 instrs (~1.4 KB) so it lives in I$.
// R4-R11 were ~2.6K-instr unrolled bodies (~21 KB) -> instruction-fetch
// starvation (all pipes <20% busy, structure/warmth-invariant ~90 us).
template <bool ATOMIC>
__global__ __launch_bounds__(512, 2) void wql_main(
    const uint4* __restrict__ x16, const unsigned* __restrict__ qw,
    const float* __restrict__ scales, const unsigned* __restrict__ qzeros,
    float* __restrict__ outp)
{
    __shared__ uint4 xs[4096];            // [128 words][32 m] = 64 KB, whole chunk

    const int tid  = threadIdx.x;
    const int bid  = blockIdx.x;
    const int nblk = bid % NBLKN;
    const int ks   = bid / NBLKN;
    const int n0   = nblk * 512;

    const int wv   = tid >> 6;            // 0..7
    const int lane = tid & 63;
    const int g    = lane >> 4;           // k-group 0..3
    const int lr   = lane & 15;
    const int gh   = g >> 1;

    // ---- stage whole x16 chunk -> LDS (zero-VALU), single barrier ----
    {
        const uint4* gs = x16 + (size_t)ks * 4096;
#pragma unroll
        for (int i = 0; i < 8; ++i)
            __builtin_amdgcn_global_load_lds(
                (const __attribute__((address_space(1))) void*)(gs + tid + i * 512),
                (__attribute__((address_space(3))) void*)(&xs[tid + i * 512]),
                16, 0, 0);
    }
    __syncthreads();                       // the ONLY barrier

#pragma unroll 1
    for (int it = 0; it < 2; ++it) {
        const int nb = n0 + it * 256 + wv * 32;
        const int r0 = nb + lr;            // sub-tile 0 n-row
        const int r1 = r0 + 16;            // sub-tile 1 n-row

        const uint4* qp0 = (const uint4*)(qw + (size_t)r0 * KWORDS + ks * 128) + g;
        const uint4* qp1 = (const uint4*)(qw + (size_t)r1 * KWORDS + ks * 128) + g;
        const float* sv0 = scales + (size_t)r0 * NKB + ks * 16 + gh;
        const float* sv1 = scales + (size_t)r1 * NKB + ks * 16 + gh;
        const uint2  zw0 = *(const uint2*)(qzeros + (size_t)r0 * 16 + ks * 2);
        const uint2  zw1 = *(const uint2*)(qzeros + (size_t)r1 * 16 + ks * 2);

        f32x4 acc00 = {0,0,0,0}, acc01 = {0,0,0,0};
        f32x4 acc10 = {0,0,0,0}, acc11 = {0,0,0,0};

#pragma unroll 1
        for (int s = 0; s < 8; ++s) {      // 8 sections x 16 words (128 k each)
            const uint4 w0 = qp0[s * 4];
            const uint4 w1 = qp1[s * 4];
            const float sf0 = sv0[2 * s];  // L1-hot after first touch
            const float sf1 = sv1[2 * s];
            // scale block in chunk = 2s+gh -> zeros word (x/y), nibble (2s+gh)&7
            const int blk = 2 * s + gh;
            const unsigned zl0 = (blk & 8) ? zw0.y : zw0.x;
            const unsigned zl1 = (blk & 8) ? zw1.y : zw1.x;
            const int sh4 = 4 * (blk & 7);
            const int zq0 = (int)((zl0 >> sh4) & 0xF);
            const int zq1 = (int)((zl1 >> sh4) & 0xF);
            const _Float16 h0 = (_Float16)sf0, h1 = (_Float16)sf1;
            const f16x2 spk0 = { h0, h0 }, spk1 = { h1, h1 };
            const _Float16 c0 = (_Float16)(-(float)(1032 + zq0));
            const _Float16 c1 = (_Float16)(-(float)(1032 + zq1));
            const f16x2 cpk0 = { c0, c0 }, cpk1 = { c1, c1 };
            const unsigned wa0[4] = { w0.x, w0.y, w0.z, w0.w };
            const unsigned wa1[4] = { w1.x, w1.y, w1.z, w1.w };
#pragma unroll
            for (int j = 0; j < 4; ++j) {
                const int wl = s * 16 + 4 * g + j;
                f16x8 b0 = __builtin_bit_cast(f16x8, xs[wl * 32 + lr]);
                f16x8 b1 = __builtin_bit_cast(f16x8, xs[wl * 32 + lr + 16]);
                f16x8 a0 = dq_word(wa0[j], spk0, cpk0);
                f16x8 a1 = dq_word(wa1[j], spk1, cpk1);
                acc00 = __builtin_amdgcn_mfma_f32_16x16x32_f16(a0, b0, acc00, 0,0,0);
                acc01 = __builtin_amdgcn_mfma_f32_16x16x32_f16(a0, b1, acc01, 0,0,0);
                acc10 = __builtin_amdgcn_mfma_f32_16x16x32_f16(a1, b0, acc10, 0,0,0);
                acc11 = __builtin_amdgcn_mfma_f32_16x16x32_f16(a1, b1, acc11, 0,0,0);
            }
        }

        // C/D: col(m)=lane&15, n-within-16 = 4*(lane>>4)+reg (validated R1..R11)
        const size_t base = (size_t)lr * N_DIM + nb + 4 * g;
        if constexpr (ATOMIC) {
#pragma unroll
            for (int r = 0; r < 4; ++r) {
                atomicAdd(outp + base + r, acc00[r]);
                atomicAdd(outp + base + 16 + r, acc10[r]);
                atomicAdd(outp + base + (size_t)16 * N_DIM + r, acc01[r]);
                atomicAdd(outp + base + (size_t)16 * N_DIM + 16 + r, acc11[r]);
            }
        } else {
            float* dst = outp + (size_t)ks * OUT_ELEMS;
            *(f32x4*)(dst + base) = acc00;
            *(f32x4*)(dst + base + 16) = acc10;
            *(f32x4*)(dst + (size_t)16 * N_DIM + base) = acc01;
            *(f32x4*)(dst + (size_t)16 * N_DIM + base + 16) = acc11;
        }
    }
}

// out = bias + sum of 8 split partials (partials L2/L3-hot right after main)
__global__ __launch_bounds__(256) void wql_reduce(const float* __restrict__ ws,
                                                  const float* __restrict__ bias,
                                                  float* __restrict__ out) {
    const int i4 = (blockIdx.x * 256 + threadIdx.x) * 4;
    const int n  = i4 % N_DIM;
    f32x4 acc = *(const f32x4*)(bias + n);
#pragma unroll
    for (int s = 0; s < NSPLIT; ++s)
        acc += *(const f32x4*)(ws + (size_t)s * OUT_ELEMS + i4);
    *(f32x4*)(out + i4) = acc;
}

extern "C" void kernel_launch(void* const* d_in, const int* in_sizes, int n_in,
                              void* d_out, int out_size, void* d_ws, size_t ws_size,
                              hipStream_t stream) {
    const float*    x      = (const float*)d_in[0];
    const unsigned* qwght  = (const unsigned*)d_in[1];
    const float*    scales = (const float*)d_in[2];
    const unsigned* qzeros = (const unsigned*)d_in[3];
    const float*    bias   = (const float*)d_in[4];
    float* out = (float*)d_out;

    uint4* x16 = (uint4*)d_ws;
    float* part = (float*)((char*)d_ws + X16_BYTES);
    const size_t need = X16_BYTES + (size_t)NSPLIT * OUT_ELEMS * sizeof(float);

    x_transform<<<dim3(KWORDS * M_DIM / 256), 256, 0, stream>>>(x, (uint4*)x16);
    if (ws_size >= need) {
        wql_main<false><<<dim3(NBLKN * NSPLIT), 512, 0, stream>>>(
            (const uint4*)x16, qwght, scales, qzeros, part);
        wql_reduce<<<dim3(OUT_ELEMS / 1024), 256, 0, stream>>>(
            part, bias, out);
    } else {
        wql_init<<<dim3(N_DIM / 256, M_DIM), 256, 0, stream>>>(bias, out);
        wql_main<true><<<dim3(NBLKN * NSPLIT), 512, 0, stream>>>(
            (const uint4*)x16, qwght, scales, qzeros, out);
    }
}